// Round 1
// baseline (2082.714 us; speedup 1.0000x reference)
//
#include <hip/hip_runtime.h>

// RVQ: z [16,64,4096] f32, codebooks [8,1024,64] f32 -> zq + 8 losses + 8 perplexities
#define S      8
#define K      1024
#define D      64
#define NVEC   65536
#define NW     2048      // blocks; now 2 waves each, codebook-split
#define NELEM  4194304.0f
#define EPSQ   1e-10f
#define DELTA  0.005f    // exact-rescan margin >> split-bf16 score error (~2e-3 worst)

typedef __attribute__((ext_vector_type(8))) short  short8;   // 8 bf16
typedef __attribute__((ext_vector_type(4))) float  float4v;  // MFMA acc

static __device__ inline unsigned short f2bf(float f) {
    unsigned int u = __float_as_uint(f);
    u = (u + 0x7FFFu + ((u >> 16) & 1u)) >> 16;
    return (unsigned short)u;
}
static __device__ inline float bf2f(unsigned short h) {
    return __uint_as_float(((unsigned int)h) << 16);
}

// ---------------------------------------------------------------------------
// Prep: (a) c2 + zero cnt; (b) interleave codebook into B-fragment streaming
// records, PRE-SCALED BY -2 so the MFMA accumulates -2*dot directly and the
// accumulator can be seeded with c2 (score = acc, no per-score fmaf).
// Scaling by -2 is exact (power of 2), bf16 hi/lo split error unchanged.
// ---------------------------------------------------------------------------
__global__ void rvq_prep(const float* __restrict__ cb,
                         unsigned short* __restrict__ cbi,
                         float* __restrict__ c2, unsigned* __restrict__ cnt) {
    int i = blockIdx.x * blockDim.x + threadIdx.x;   // 0..32767
    if (i < S * K) {   // c2 + cnt zero
        const float* row = cb + (size_t)i * D;
        float a0 = 0.f, a1 = 0.f, a2 = 0.f, a3 = 0.f;
#pragma unroll
        for (int d = 0; d < D; d += 4) {
            a0 = fmaf(row[d+0], row[d+0], a0);
            a1 = fmaf(row[d+1], row[d+1], a1);
            a2 = fmaf(row[d+2], row[d+2], a2);
            a3 = fmaf(row[d+3], row[d+3], a3);
        }
        c2[i] = (a0 + a1) + (a2 + a3);
        cnt[i] = 0u;
    }
    // interleave: i = s*4096 + tau*64 + l
    int s  = i >> 12;
    int tau = (i >> 6) & 63;
    int l  = i & 63;
    int m  = l & 15, qq = l >> 4;
    const float* row = cb + (size_t)(s * K + tau * 16 + m) * D;
    short8 h0h, h0l, h1h, h1l;
#pragma unroll
    for (int e = 0; e < 8; ++e) {
        float x = -2.0f * row[qq * 8 + e];
        unsigned short h = f2bf(x);
        h0h[e] = (short)h; h0l[e] = (short)f2bf(x - bf2f(h));
        float y = -2.0f * row[32 + qq * 8 + e];
        unsigned short g = f2bf(y);
        h1h[e] = (short)g; h1l[e] = (short)f2bf(y - bf2f(g));
    }
    unsigned short* rec = cbi + (size_t)(s * 64 + tau) * 2048 + l * 8;
    *(short8*)(rec +    0) = h0h;
    *(short8*)(rec +  512) = h1h;
    *(short8*)(rec + 1024) = h0l;
    *(short8*)(rec + 1536) = h1l;
}

// ---------------------------------------------------------------------------
// Main: 2 waves per block, 32 vectors per block (both waves hold the SAME
// 32 vectors' residuals; wave w scans codebook tiles [w*32, w*32+32)).
// Doubles resident waves 8->16/CU for latency hiding WITHOUT increasing
// L2 codebook traffic. Top-2+index merged across waves via tiny LDS
// (stage-parity double-buffered, 1 barrier/stage). Scores come straight
// out of the accumulator (B pre-scaled -2, acc seeded with c2).
// Both waves compute bit-identical merged winners -> rescue/update stay
// convergent; wave 0 owns loss store + histogram; epilogue split by set.
// ---------------------------------------------------------------------------
__global__ __launch_bounds__(128, 4)
void rvq_main(const float* __restrict__ z, const float* __restrict__ cbf,
              const unsigned short* __restrict__ cbi,
              const float* __restrict__ c2, float* __restrict__ zq,
              float* __restrict__ lossp, unsigned* __restrict__ cnt) {
    const int tid  = threadIdx.x;
    const int lane = tid & 63;
    const int w    = tid >> 6;              // wave id 0/1
    const int m    = lane & 15;
    const int q    = lane >> 4;
    const int wid  = blockIdx.x;
    const int vbase = wid * 32;
    const int b    = vbase >> 12;
    const int ta   = (vbase & 4095) + m;    // set-a t
    const int tb   = ta + 16;               // set-b t
    const size_t zrow = ((size_t)(b * 64)) << 12;
    const int tbase = w * 32;               // this wave's tile range

    __shared__ float lb1[2][2][2][16];      // [parity][wave][set][row]
    __shared__ float lb2[2][2][2][16];
    __shared__ int   lk1[2][2][2][16];

    float ra0[8], ra1[8], rb0[8], rb1[8];
#pragma unroll
    for (int i = 0; i < 8; ++i) {
        ra0[i] = z[zrow + ((size_t)(q*8+i)    << 12) + ta];
        ra1[i] = z[zrow + ((size_t)(32+q*8+i) << 12) + ta];
        rb0[i] = z[zrow + ((size_t)(q*8+i)    << 12) + tb];
        rb1[i] = z[zrow + ((size_t)(32+q*8+i) << 12) + tb];
    }

#define LOADTILE(B0v, B1v, B2v, B3v, CCv, tt) {                              \
        const unsigned short* p_ = recs + (size_t)(tt) * 2048 + lane * 8;    \
        B0v = *(const short8*)(p_);                                          \
        B1v = *(const short8*)(p_ + 512);                                    \
        B2v = *(const short8*)(p_ + 1024);                                   \
        B3v = *(const short8*)(p_ + 1536);                                   \
        CCv = c2s[(tt) * 16 + m]; }

#pragma unroll 1
    for (int s = 0; s < S; ++s) {
        // split residuals to bf16 hi/lo A-fragments
        short8 xa0h, xa0l, xa1h, xa1l, xb0h, xb0l, xb1h, xb1l;
#pragma unroll
        for (int i = 0; i < 8; ++i) {
            unsigned short h;
            h = f2bf(ra0[i]); xa0h[i] = (short)h; xa0l[i] = (short)f2bf(ra0[i] - bf2f(h));
            h = f2bf(ra1[i]); xa1h[i] = (short)h; xa1l[i] = (short)f2bf(ra1[i] - bf2f(h));
            h = f2bf(rb0[i]); xb0h[i] = (short)h; xb0l[i] = (short)f2bf(rb0[i] - bf2f(h));
            h = f2bf(rb1[i]); xb1h[i] = (short)h; xb1l[i] = (short)f2bf(rb1[i] - bf2f(h));
        }

        float b1a[4], b2a[4], b1b[4], b2b[4];
        int   k1a[4], k1b[4];
#pragma unroll
        for (int j = 0; j < 4; ++j) {
            b1a[j] = 3.4e38f; b2a[j] = 3.4e38f; k1a[j] = 0;
            b1b[j] = 3.4e38f; b2b[j] = 3.4e38f; k1b[j] = 0;
        }

        const unsigned short* recs = cbi + (size_t)s * 131072;
        const float*          c2s  = c2 + s * K;

        short8 A0, A1, A2, A3, C0, C1, C2, C3;   // two banks
        float  ca, cb2;
        LOADTILE(A0, A1, A2, A3, ca,  tbase + 0);
        LOADTILE(C0, C1, C2, C3, cb2, tbase + 1);

#pragma unroll 1
        for (int tau = 0; tau < 32; tau += 2) {
            // ---- bank A: tile tbase+tau ----
            {
                short8 bh0 = A0, bh1 = A1, bl0 = A2, bl1 = A3;
                float  c2v = ca;
                if (tau + 2 < 32) LOADTILE(A0, A1, A2, A3, ca, tbase + tau + 2);
                float4v aa = {c2v, c2v, c2v, c2v}, ab = {c2v, c2v, c2v, c2v};
                aa = __builtin_amdgcn_mfma_f32_16x16x32_bf16(xa0h, bh0, aa, 0,0,0);
                aa = __builtin_amdgcn_mfma_f32_16x16x32_bf16(xa0l, bh0, aa, 0,0,0);
                aa = __builtin_amdgcn_mfma_f32_16x16x32_bf16(xa0h, bl0, aa, 0,0,0);
                aa = __builtin_amdgcn_mfma_f32_16x16x32_bf16(xa1h, bh1, aa, 0,0,0);
                aa = __builtin_amdgcn_mfma_f32_16x16x32_bf16(xa1l, bh1, aa, 0,0,0);
                aa = __builtin_amdgcn_mfma_f32_16x16x32_bf16(xa1h, bl1, aa, 0,0,0);
                ab = __builtin_amdgcn_mfma_f32_16x16x32_bf16(xb0h, bh0, ab, 0,0,0);
                ab = __builtin_amdgcn_mfma_f32_16x16x32_bf16(xb0l, bh0, ab, 0,0,0);
                ab = __builtin_amdgcn_mfma_f32_16x16x32_bf16(xb0h, bl0, ab, 0,0,0);
                ab = __builtin_amdgcn_mfma_f32_16x16x32_bf16(xb1h, bh1, ab, 0,0,0);
                ab = __builtin_amdgcn_mfma_f32_16x16x32_bf16(xb1l, bh1, ab, 0,0,0);
                ab = __builtin_amdgcn_mfma_f32_16x16x32_bf16(xb1h, bl1, ab, 0,0,0);
                int ncol = (tbase + tau) * 16 + m;
#pragma unroll
                for (int j = 0; j < 4; ++j) {
                    float sa = aa[j];
                    b2a[j] = fminf(b2a[j], fmaxf(sa, b1a[j]));
                    k1a[j] = (sa < b1a[j]) ? ncol : k1a[j];
                    b1a[j] = fminf(sa, b1a[j]);
                    float sb = ab[j];
                    b2b[j] = fminf(b2b[j], fmaxf(sb, b1b[j]));
                    k1b[j] = (sb < b1b[j]) ? ncol : k1b[j];
                    b1b[j] = fminf(sb, b1b[j]);
                }
            }
            // ---- bank B: tile tbase+tau+1 ----
            {
                short8 bh0 = C0, bh1 = C1, bl0 = C2, bl1 = C3;
                float  c2v = cb2;
                if (tau + 3 < 32) LOADTILE(C0, C1, C2, C3, cb2, tbase + tau + 3);
                float4v aa = {c2v, c2v, c2v, c2v}, ab = {c2v, c2v, c2v, c2v};
                aa = __builtin_amdgcn_mfma_f32_16x16x32_bf16(xa0h, bh0, aa, 0,0,0);
                aa = __builtin_amdgcn_mfma_f32_16x16x32_bf16(xa0l, bh0, aa, 0,0,0);
                aa = __builtin_amdgcn_mfma_f32_16x16x32_bf16(xa0h, bl0, aa, 0,0,0);
                aa = __builtin_amdgcn_mfma_f32_16x16x32_bf16(xa1h, bh1, aa, 0,0,0);
                aa = __builtin_amdgcn_mfma_f32_16x16x32_bf16(xa1l, bh1, aa, 0,0,0);
                aa = __builtin_amdgcn_mfma_f32_16x16x32_bf16(xa1h, bl1, aa, 0,0,0);
                ab = __builtin_amdgcn_mfma_f32_16x16x32_bf16(xb0h, bh0, ab, 0,0,0);
                ab = __builtin_amdgcn_mfma_f32_16x16x32_bf16(xb0l, bh0, ab, 0,0,0);
                ab = __builtin_amdgcn_mfma_f32_16x16x32_bf16(xb0h, bl0, ab, 0,0,0);
                ab = __builtin_amdgcn_mfma_f32_16x16x32_bf16(xb1h, bh1, ab, 0,0,0);
                ab = __builtin_amdgcn_mfma_f32_16x16x32_bf16(xb1l, bh1, ab, 0,0,0);
                ab = __builtin_amdgcn_mfma_f32_16x16x32_bf16(xb1h, bl1, ab, 0,0,0);
                int ncol = (tbase + tau + 1) * 16 + m;
#pragma unroll
                for (int j = 0; j < 4; ++j) {
                    float sa = aa[j];
                    b2a[j] = fminf(b2a[j], fmaxf(sa, b1a[j]));
                    k1a[j] = (sa < b1a[j]) ? ncol : k1a[j];
                    b1a[j] = fminf(sa, b1a[j]);
                    float sb = ab[j];
                    b2b[j] = fminf(b2b[j], fmaxf(sb, b1b[j]));
                    k1b[j] = (sb < b1b[j]) ? ncol : k1b[j];
                    b1b[j] = fminf(sb, b1b[j]);
                }
            }
        }

        // ---- reduce across the 16 col-lanes (k-tie: lowest k) ----
#pragma unroll
        for (int off = 1; off < 16; off <<= 1) {
#pragma unroll
            for (int j = 0; j < 4; ++j) {
                float o1 = __shfl_xor(b1a[j], off); int ok = __shfl_xor(k1a[j], off);
                float o2 = __shfl_xor(b2a[j], off);
                float n2 = fminf(fminf(b2a[j], o2), fmaxf(b1a[j], o1));
                bool tk = (o1 < b1a[j]) || (o1 == b1a[j] && ok < k1a[j]);
                k1a[j] = tk ? ok : k1a[j]; b1a[j] = fminf(b1a[j], o1); b2a[j] = n2;
                o1 = __shfl_xor(b1b[j], off); ok = __shfl_xor(k1b[j], off);
                o2 = __shfl_xor(b2b[j], off);
                n2 = fminf(fminf(b2b[j], o2), fmaxf(b1b[j], o1));
                tk = (o1 < b1b[j]) || (o1 == b1b[j] && ok < k1b[j]);
                k1b[j] = tk ? ok : k1b[j]; b1b[j] = fminf(b1b[j], o1); b2b[j] = n2;
            }
        }

        // ---- cross-wave merge via LDS (parity double-buffered, 1 barrier) --
        {
            int par = s & 1;
            if (m == 0) {
#pragma unroll
                for (int j = 0; j < 4; ++j) {
                    lb1[par][w][0][q*4+j] = b1a[j];
                    lb2[par][w][0][q*4+j] = b2a[j];
                    lk1[par][w][0][q*4+j] = k1a[j];
                    lb1[par][w][1][q*4+j] = b1b[j];
                    lb2[par][w][1][q*4+j] = b2b[j];
                    lk1[par][w][1][q*4+j] = k1b[j];
                }
            }
            __syncthreads();
            int ow = w ^ 1;
#pragma unroll
            for (int j = 0; j < 4; ++j) {
                float o1 = lb1[par][ow][0][q*4+j];
                float o2 = lb2[par][ow][0][q*4+j];
                int   ok = lk1[par][ow][0][q*4+j];
                float n2 = fminf(fminf(b2a[j], o2), fmaxf(b1a[j], o1));
                bool tk = (o1 < b1a[j]) || (o1 == b1a[j] && ok < k1a[j]);
                k1a[j] = tk ? ok : k1a[j]; b1a[j] = fminf(b1a[j], o1); b2a[j] = n2;
                o1 = lb1[par][ow][1][q*4+j];
                o2 = lb2[par][ow][1][q*4+j];
                ok = lk1[par][ow][1][q*4+j];
                n2 = fminf(fminf(b2b[j], o2), fmaxf(b1b[j], o1));
                tk = (o1 < b1b[j]) || (o1 == b1b[j] && ok < k1b[j]);
                k1b[j] = tk ? ok : k1b[j]; b1b[j] = fminf(b1b[j], o1); b2b[j] = n2;
            }
        }

        // ---- δ-rescue: exact fp32 rescan of ambiguous rows (rare) ----
        // both waves run identically on merged values -> stays convergent
        const float* cr0 = cbf + (size_t)s * 65536;
#define RESCUE(b1X, b2X, k1X, R0, R1)                                         \
        for (int j = 0; j < 4; ++j) {                                         \
            unsigned long long mask = __ballot(b2X[j] - b1X[j] < DELTA);      \
            while (mask) {                                                    \
                int lq = (int)(__builtin_ctzll(mask)) >> 4;                   \
                mask &= ~(0xFFFFULL << (lq * 16));                            \
                int mrow = lq * 4 + j;                                        \
                float bd = 3.4e38f; int bk = 0;                               \
                for (int cc = 0; cc < 16; ++cc) {                             \
                    int n = cc * 64 + lane;                                   \
                    const float* crow = cr0 + (size_t)n * 64;                 \
                    float dot = 0.f;                                          \
                    for (int p = 0; p < 4; ++p) {                             \
                        for (int i = 0; i < 8; ++i)                           \
                            dot = fmaf(__shfl(R0[i], mrow + 16*p), crow[p*8+i], dot); \
                        for (int i = 0; i < 8; ++i)                           \
                            dot = fmaf(__shfl(R1[i], mrow + 16*p), crow[32+p*8+i], dot); \
                    }                                                         \
                    float sc = c2s[n] - 2.f * dot;                            \
                    if (sc < bd) { bd = sc; bk = n; }                         \
                }                                                             \
                for (int off = 1; off < 64; off <<= 1) {                      \
                    float ob = __shfl_xor(bd, off); int ok = __shfl_xor(bk, off); \
                    bool tk = (ob < bd) || (ob == bd && ok < bk);             \
                    bk = tk ? ok : bk; bd = fminf(bd, ob);                    \
                }                                                             \
                if (q == lq) k1X[j] = bk;                                     \
            }                                                                 \
        }
        RESCUE(b1a, b2a, k1a, ra0, ra1)
        RESCUE(b1b, b2b, k1b, rb0, rb1)
#undef RESCUE

        // ---- transpose winners to per-lane rows (row = m), convergent ----
        int mm = m & 3, src = (m >> 2) * 16;
        int wa0 = __shfl(k1a[0], src), wa1 = __shfl(k1a[1], src);
        int wa2 = __shfl(k1a[2], src), wa3 = __shfl(k1a[3], src);
        int bka = (mm == 0) ? wa0 : (mm == 1) ? wa1 : (mm == 2) ? wa2 : wa3;
        int wb0 = __shfl(k1b[0], src), wb1 = __shfl(k1b[1], src);
        int wb2 = __shfl(k1b[2], src), wb3 = __shfl(k1b[3], src);
        int bkb = (mm == 0) ? wb0 : (mm == 1) ? wb1 : (mm == 2) ? wb2 : wb3;

        // ---- fp32 residual update (both waves, identical) ----
        const float* qa = cbf + (size_t)s * 65536 + (size_t)bka * 64;
        const float* qb = cbf + (size_t)s * 65536 + (size_t)bkb * 64;
#pragma unroll
        for (int i = 0; i < 8; ++i) {
            ra0[i] -= qa[q*8+i];  ra1[i] -= qa[32+q*8+i];
            rb0[i] -= qb[q*8+i];  rb1[i] -= qb[32+q*8+i];
        }

        // ---- loss: wave 0 stores (identical residuals in both waves) ----
        if (w == 0) {
            float ls = 0.f;
#pragma unroll
            for (int i = 0; i < 8; ++i) {
                ls = fmaf(ra0[i], ra0[i], ls); ls = fmaf(ra1[i], ra1[i], ls);
                ls = fmaf(rb0[i], rb0[i], ls); ls = fmaf(rb1[i], rb1[i], ls);
            }
#pragma unroll
            for (int off = 1; off < 64; off <<= 1) ls += __shfl_xor(ls, off);
            if (lane == 0) lossp[s * NW + wid] = ls;

            // ---- histogram: once per vector ----
            if (q == 0) {
                atomicAdd(&cnt[s * K + bka], 1u);   // vector vbase+m
                atomicAdd(&cnt[s * K + bkb], 1u);   // vector vbase+16+m
            }
        }
    }
#undef LOADTILE

    // ---- epilogue: zq = z - r_final, stores split by set across waves ----
    if (w == 0) {
#pragma unroll
        for (int i = 0; i < 8; ++i) {
            size_t a0 = zrow + ((size_t)(q*8+i)    << 12) + ta;
            size_t a1 = zrow + ((size_t)(32+q*8+i) << 12) + ta;
            zq[a0] = z[a0] - ra0[i];
            zq[a1] = z[a1] - ra1[i];
        }
    } else {
#pragma unroll
        for (int i = 0; i < 8; ++i) {
            size_t a2 = zrow + ((size_t)(q*8+i)    << 12) + tb;
            size_t a3 = zrow + ((size_t)(32+q*8+i) << 12) + tb;
            zq[a2] = z[a2] - rb0[i];
            zq[a3] = z[a3] - rb1[i];
        }
    }
}

// ---------------------------------------------------------------------------
// Finalize: losses (mean of summed wave partials) + perplexities
// ---------------------------------------------------------------------------
__global__ void rvq_finalize(const float* __restrict__ lossp,
                             const unsigned* __restrict__ cnt,
                             float* __restrict__ out_loss,
                             float* __restrict__ out_perp) {
    const int s   = blockIdx.x;
    const int tid = threadIdx.x;
    float ent = 0.f, lsum = 0.f;
    for (int i = tid; i < K; i += 256) {
        float p = (float)cnt[s * K + i] * (1.0f / 65536.0f);
        ent += p * logf(p + EPSQ);
    }
    for (int i = tid; i < NW; i += 256) lsum += lossp[s * NW + i];
    __shared__ float redE[4], redL[4];
#pragma unroll
    for (int off = 32; off > 0; off >>= 1) {
        ent  += __shfl_down(ent, off);
        lsum += __shfl_down(lsum, off);
    }
    if ((tid & 63) == 0) { redE[tid >> 6] = ent; redL[tid >> 6] = lsum; }
    __syncthreads();
    if (tid == 0) {
        float te = redE[0] + redE[1] + redE[2] + redE[3];
        float tl = redL[0] + redL[1] + redL[2] + redL[3];
        out_perp[s] = expf(-te);
        out_loss[s] = tl * (1.0f / NELEM);
    }
}

// ---------------------------------------------------------------------------
extern "C" void kernel_launch(void* const* d_in, const int* in_sizes, int n_in,
                              void* d_out, int out_size, void* d_ws, size_t ws_size,
                              hipStream_t stream) {
    const float* z  = (const float*)d_in[0];
    const float* cb = (const float*)d_in[1];

    float* zq       = (float*)d_out;
    float* out_loss = zq + 4194304;
    float* out_perp = out_loss + 8;

    // ws: cbi 2 MB | c2 32 KB | cnt 32 KB | lossp 64 KB
    char* ws = (char*)d_ws;
    unsigned short* cbi = (unsigned short*)(ws);
    float*    c2    = (float*)(ws + 2097152);
    unsigned* cnt   = (unsigned*)(ws + 2129920);
    float*    lossp = (float*)(ws + 2162688);

    hipLaunchKernelGGL(rvq_prep,     dim3(128),  dim3(256), 0, stream, cb, cbi, c2, cnt);
    hipLaunchKernelGGL(rvq_main,     dim3(NW),   dim3(128), 0, stream, z, cb, cbi, c2, zq, lossp, cnt);
    hipLaunchKernelGGL(rvq_finalize, dim3(S),    dim3(256), 0, stream, lossp, cnt, out_loss, out_perp);
}

// Round 2
// 447.800 us; speedup vs baseline: 4.6510x; 4.6510x over previous
//
#include <hip/hip_runtime.h>

// RVQ: z [16,64,4096] f32, codebooks [8,1024,64] f32 -> zq + 8 losses + 8 perplexities
#define S      8
#define K      1024
#define D      64
#define NVEC   65536
#define NW     2048      // blocks; 2 waves each, codebook-split
#define NELEM  4194304.0f
#define EPSQ   1e-10f
#define DELTA  0.005f    // exact-rescan margin >> split-bf16 score error (~2e-3 worst)

typedef __attribute__((ext_vector_type(8))) short  short8;   // 8 bf16
typedef __attribute__((ext_vector_type(4))) float  float4v;  // MFMA acc

static __device__ inline unsigned short f2bf(float f) {
    unsigned int u = __float_as_uint(f);
    u = (u + 0x7FFFu + ((u >> 16) & 1u)) >> 16;
    return (unsigned short)u;
}
static __device__ inline float bf2f(unsigned short h) {
    return __uint_as_float(((unsigned int)h) << 16);
}

// ---------------------------------------------------------------------------
// Prep: (a) c2 + zero cnt; (b) interleave codebook into B-fragment streaming
// records, PRE-SCALED BY -2 so the MFMA accumulates -2*dot directly and the
// accumulator can be seeded with c2 (score = acc, no per-score fmaf).
// Scaling by -2 is exact (power of 2), bf16 hi/lo split error unchanged.
// ---------------------------------------------------------------------------
__global__ void rvq_prep(const float* __restrict__ cb,
                         unsigned short* __restrict__ cbi,
                         float* __restrict__ c2, unsigned* __restrict__ cnt) {
    int i = blockIdx.x * blockDim.x + threadIdx.x;   // 0..32767
    if (i < S * K) {   // c2 + cnt zero
        const float* row = cb + (size_t)i * D;
        float a0 = 0.f, a1 = 0.f, a2 = 0.f, a3 = 0.f;
#pragma unroll
        for (int d = 0; d < D; d += 4) {
            a0 = fmaf(row[d+0], row[d+0], a0);
            a1 = fmaf(row[d+1], row[d+1], a1);
            a2 = fmaf(row[d+2], row[d+2], a2);
            a3 = fmaf(row[d+3], row[d+3], a3);
        }
        c2[i] = (a0 + a1) + (a2 + a3);
        cnt[i] = 0u;
    }
    // interleave: i = s*4096 + tau*64 + l
    int s  = i >> 12;
    int tau = (i >> 6) & 63;
    int l  = i & 63;
    int m  = l & 15, qq = l >> 4;
    const float* row = cb + (size_t)(s * K + tau * 16 + m) * D;
    short8 h0h, h0l, h1h, h1l;
#pragma unroll
    for (int e = 0; e < 8; ++e) {
        float x = -2.0f * row[qq * 8 + e];
        unsigned short h = f2bf(x);
        h0h[e] = (short)h; h0l[e] = (short)f2bf(x - bf2f(h));
        float y = -2.0f * row[32 + qq * 8 + e];
        unsigned short g = f2bf(y);
        h1h[e] = (short)g; h1l[e] = (short)f2bf(y - bf2f(g));
    }
    unsigned short* rec = cbi + (size_t)(s * 64 + tau) * 2048 + l * 8;
    *(short8*)(rec +    0) = h0h;
    *(short8*)(rec +  512) = h1h;
    *(short8*)(rec + 1024) = h0l;
    *(short8*)(rec + 1536) = h1l;
}

// ---------------------------------------------------------------------------
// Main: 2 waves per block, 32 vectors per block (both waves hold the SAME
// 32 vectors' residuals; wave w scans codebook tiles [w*32, w*32+32)).
// Doubles resident waves 8->16/CU for latency hiding WITHOUT increasing
// L2 codebook traffic. Top-2+index merged across waves via tiny LDS.
//
// launch_bounds NOTE (R1 post-mortem): (128,4) capped VGPRs at 64 -> the
// ~124-reg working set spilled to scratch -> 4.7 GB/dispatch HBM traffic,
// 2083 us. Empirically arg2 acts on a blocks/EU basis for multi-wave
// blocks: (128,2) -> 4 waves/EU cap -> 128 VGPRs, which fits. Do NOT
// raise arg2 above 2 for 128-thread blocks here.
// ---------------------------------------------------------------------------
__global__ __launch_bounds__(128, 2)
void rvq_main(const float* __restrict__ z, const float* __restrict__ cbf,
              const unsigned short* __restrict__ cbi,
              const float* __restrict__ c2, float* __restrict__ zq,
              float* __restrict__ lossp, unsigned* __restrict__ cnt) {
    const int tid  = threadIdx.x;
    const int lane = tid & 63;
    const int w    = tid >> 6;              // wave id 0/1
    const int m    = lane & 15;
    const int q    = lane >> 4;
    const int wid  = blockIdx.x;
    const int vbase = wid * 32;
    const int b    = vbase >> 12;
    const int ta   = (vbase & 4095) + m;    // set-a t
    const int tb   = ta + 16;               // set-b t
    const size_t zrow = ((size_t)(b * 64)) << 12;
    const int tbase = w * 32;               // this wave's tile range

    __shared__ float lb1[2][2][2][16];      // [parity][wave][set][row]
    __shared__ float lb2[2][2][2][16];
    __shared__ int   lk1[2][2][2][16];

    float ra0[8], ra1[8], rb0[8], rb1[8];
#pragma unroll
    for (int i = 0; i < 8; ++i) {
        ra0[i] = z[zrow + ((size_t)(q*8+i)    << 12) + ta];
        ra1[i] = z[zrow + ((size_t)(32+q*8+i) << 12) + ta];
        rb0[i] = z[zrow + ((size_t)(q*8+i)    << 12) + tb];
        rb1[i] = z[zrow + ((size_t)(32+q*8+i) << 12) + tb];
    }

#define LOADTILE(B0v, B1v, B2v, B3v, CCv, tt) {                              \
        const unsigned short* p_ = recs + (size_t)(tt) * 2048 + lane * 8;    \
        B0v = *(const short8*)(p_);                                          \
        B1v = *(const short8*)(p_ + 512);                                    \
        B2v = *(const short8*)(p_ + 1024);                                   \
        B3v = *(const short8*)(p_ + 1536);                                   \
        CCv = c2s[(tt) * 16 + m]; }

#pragma unroll 1
    for (int s = 0; s < S; ++s) {
        // split residuals to bf16 hi/lo A-fragments
        short8 xa0h, xa0l, xa1h, xa1l, xb0h, xb0l, xb1h, xb1l;
#pragma unroll
        for (int i = 0; i < 8; ++i) {
            unsigned short h;
            h = f2bf(ra0[i]); xa0h[i] = (short)h; xa0l[i] = (short)f2bf(ra0[i] - bf2f(h));
            h = f2bf(ra1[i]); xa1h[i] = (short)h; xa1l[i] = (short)f2bf(ra1[i] - bf2f(h));
            h = f2bf(rb0[i]); xb0h[i] = (short)h; xb0l[i] = (short)f2bf(rb0[i] - bf2f(h));
            h = f2bf(rb1[i]); xb1h[i] = (short)h; xb1l[i] = (short)f2bf(rb1[i] - bf2f(h));
        }

        float b1a[4], b2a[4], b1b[4], b2b[4];
        int   k1a[4], k1b[4];
#pragma unroll
        for (int j = 0; j < 4; ++j) {
            b1a[j] = 3.4e38f; b2a[j] = 3.4e38f; k1a[j] = 0;
            b1b[j] = 3.4e38f; b2b[j] = 3.4e38f; k1b[j] = 0;
        }

        const unsigned short* recs = cbi + (size_t)s * 131072;
        const float*          c2s  = c2 + s * K;

        short8 A0, A1, A2, A3, C0, C1, C2, C3;   // two banks
        float  ca, cb2;
        LOADTILE(A0, A1, A2, A3, ca,  tbase + 0);
        LOADTILE(C0, C1, C2, C3, cb2, tbase + 1);

#pragma unroll 1
        for (int tau = 0; tau < 32; tau += 2) {
            // ---- bank A: tile tbase+tau ----
            {
                short8 bh0 = A0, bh1 = A1, bl0 = A2, bl1 = A3;
                float  c2v = ca;
                if (tau + 2 < 32) LOADTILE(A0, A1, A2, A3, ca, tbase + tau + 2);
                float4v aa = {c2v, c2v, c2v, c2v}, ab = {c2v, c2v, c2v, c2v};
                aa = __builtin_amdgcn_mfma_f32_16x16x32_bf16(xa0h, bh0, aa, 0,0,0);
                aa = __builtin_amdgcn_mfma_f32_16x16x32_bf16(xa0l, bh0, aa, 0,0,0);
                aa = __builtin_amdgcn_mfma_f32_16x16x32_bf16(xa0h, bl0, aa, 0,0,0);
                aa = __builtin_amdgcn_mfma_f32_16x16x32_bf16(xa1h, bh1, aa, 0,0,0);
                aa = __builtin_amdgcn_mfma_f32_16x16x32_bf16(xa1l, bh1, aa, 0,0,0);
                aa = __builtin_amdgcn_mfma_f32_16x16x32_bf16(xa1h, bl1, aa, 0,0,0);
                ab = __builtin_amdgcn_mfma_f32_16x16x32_bf16(xb0h, bh0, ab, 0,0,0);
                ab = __builtin_amdgcn_mfma_f32_16x16x32_bf16(xb0l, bh0, ab, 0,0,0);
                ab = __builtin_amdgcn_mfma_f32_16x16x32_bf16(xb0h, bl0, ab, 0,0,0);
                ab = __builtin_amdgcn_mfma_f32_16x16x32_bf16(xb1h, bh1, ab, 0,0,0);
                ab = __builtin_amdgcn_mfma_f32_16x16x32_bf16(xb1l, bh1, ab, 0,0,0);
                ab = __builtin_amdgcn_mfma_f32_16x16x32_bf16(xb1h, bl1, ab, 0,0,0);
                int ncol = (tbase + tau) * 16 + m;
#pragma unroll
                for (int j = 0; j < 4; ++j) {
                    float sa = aa[j];
                    b2a[j] = fminf(b2a[j], fmaxf(sa, b1a[j]));
                    k1a[j] = (sa < b1a[j]) ? ncol : k1a[j];
                    b1a[j] = fminf(sa, b1a[j]);
                    float sb = ab[j];
                    b2b[j] = fminf(b2b[j], fmaxf(sb, b1b[j]));
                    k1b[j] = (sb < b1b[j]) ? ncol : k1b[j];
                    b1b[j] = fminf(sb, b1b[j]);
                }
            }
            // ---- bank B: tile tbase+tau+1 ----
            {
                short8 bh0 = C0, bh1 = C1, bl0 = C2, bl1 = C3;
                float  c2v = cb2;
                if (tau + 3 < 32) LOADTILE(C0, C1, C2, C3, cb2, tbase + tau + 3);
                float4v aa = {c2v, c2v, c2v, c2v}, ab = {c2v, c2v, c2v, c2v};
                aa = __builtin_amdgcn_mfma_f32_16x16x32_bf16(xa0h, bh0, aa, 0,0,0);
                aa = __builtin_amdgcn_mfma_f32_16x16x32_bf16(xa0l, bh0, aa, 0,0,0);
                aa = __builtin_amdgcn_mfma_f32_16x16x32_bf16(xa0h, bl0, aa, 0,0,0);
                aa = __builtin_amdgcn_mfma_f32_16x16x32_bf16(xa1h, bh1, aa, 0,0,0);
                aa = __builtin_amdgcn_mfma_f32_16x16x32_bf16(xa1l, bh1, aa, 0,0,0);
                aa = __builtin_amdgcn_mfma_f32_16x16x32_bf16(xa1h, bl1, aa, 0,0,0);
                ab = __builtin_amdgcn_mfma_f32_16x16x32_bf16(xb0h, bh0, ab, 0,0,0);
                ab = __builtin_amdgcn_mfma_f32_16x16x32_bf16(xb0l, bh0, ab, 0,0,0);
                ab = __builtin_amdgcn_mfma_f32_16x16x32_bf16(xb0h, bl0, ab, 0,0,0);
                ab = __builtin_amdgcn_mfma_f32_16x16x32_bf16(xb1h, bh1, ab, 0,0,0);
                ab = __builtin_amdgcn_mfma_f32_16x16x32_bf16(xb1l, bh1, ab, 0,0,0);
                ab = __builtin_amdgcn_mfma_f32_16x16x32_bf16(xb1h, bl1, ab, 0,0,0);
                int ncol = (tbase + tau + 1) * 16 + m;
#pragma unroll
                for (int j = 0; j < 4; ++j) {
                    float sa = aa[j];
                    b2a[j] = fminf(b2a[j], fmaxf(sa, b1a[j]));
                    k1a[j] = (sa < b1a[j]) ? ncol : k1a[j];
                    b1a[j] = fminf(sa, b1a[j]);
                    float sb = ab[j];
                    b2b[j] = fminf(b2b[j], fmaxf(sb, b1b[j]));
                    k1b[j] = (sb < b1b[j]) ? ncol : k1b[j];
                    b1b[j] = fminf(sb, b1b[j]);
                }
            }
        }

        // ---- reduce across the 16 col-lanes (k-tie: lowest k) ----
#pragma unroll
        for (int off = 1; off < 16; off <<= 1) {
#pragma unroll
            for (int j = 0; j < 4; ++j) {
                float o1 = __shfl_xor(b1a[j], off); int ok = __shfl_xor(k1a[j], off);
                float o2 = __shfl_xor(b2a[j], off);
                float n2 = fminf(fminf(b2a[j], o2), fmaxf(b1a[j], o1));
                bool tk = (o1 < b1a[j]) || (o1 == b1a[j] && ok < k1a[j]);
                k1a[j] = tk ? ok : k1a[j]; b1a[j] = fminf(b1a[j], o1); b2a[j] = n2;
                o1 = __shfl_xor(b1b[j], off); ok = __shfl_xor(k1b[j], off);
                o2 = __shfl_xor(b2b[j], off);
                n2 = fminf(fminf(b2b[j], o2), fmaxf(b1b[j], o1));
                tk = (o1 < b1b[j]) || (o1 == b1b[j] && ok < k1b[j]);
                k1b[j] = tk ? ok : k1b[j]; b1b[j] = fminf(b1b[j], o1); b2b[j] = n2;
            }
        }

        // ---- cross-wave merge via LDS (parity double-buffered, 1 barrier) --
        {
            int par = s & 1;
            if (m == 0) {
#pragma unroll
                for (int j = 0; j < 4; ++j) {
                    lb1[par][w][0][q*4+j] = b1a[j];
                    lb2[par][w][0][q*4+j] = b2a[j];
                    lk1[par][w][0][q*4+j] = k1a[j];
                    lb1[par][w][1][q*4+j] = b1b[j];
                    lb2[par][w][1][q*4+j] = b2b[j];
                    lk1[par][w][1][q*4+j] = k1b[j];
                }
            }
            __syncthreads();
            int ow = w ^ 1;
#pragma unroll
            for (int j = 0; j < 4; ++j) {
                float o1 = lb1[par][ow][0][q*4+j];
                float o2 = lb2[par][ow][0][q*4+j];
                int   ok = lk1[par][ow][0][q*4+j];
                float n2 = fminf(fminf(b2a[j], o2), fmaxf(b1a[j], o1));
                bool tk = (o1 < b1a[j]) || (o1 == b1a[j] && ok < k1a[j]);
                k1a[j] = tk ? ok : k1a[j]; b1a[j] = fminf(b1a[j], o1); b2a[j] = n2;
                o1 = lb1[par][ow][1][q*4+j];
                o2 = lb2[par][ow][1][q*4+j];
                ok = lk1[par][ow][1][q*4+j];
                n2 = fminf(fminf(b2b[j], o2), fmaxf(b1b[j], o1));
                tk = (o1 < b1b[j]) || (o1 == b1b[j] && ok < k1b[j]);
                k1b[j] = tk ? ok : k1b[j]; b1b[j] = fminf(b1b[j], o1); b2b[j] = n2;
            }
        }

        // ---- δ-rescue: exact fp32 rescan of ambiguous rows (rare) ----
        // both waves run identically on merged values -> stays convergent
        const float* cr0 = cbf + (size_t)s * 65536;
#define RESCUE(b1X, b2X, k1X, R0, R1)                                         \
        for (int j = 0; j < 4; ++j) {                                         \
            unsigned long long mask = __ballot(b2X[j] - b1X[j] < DELTA);      \
            while (mask) {                                                    \
                int lq = (int)(__builtin_ctzll(mask)) >> 4;                   \
                mask &= ~(0xFFFFULL << (lq * 16));                            \
                int mrow = lq * 4 + j;                                        \
                float bd = 3.4e38f; int bk = 0;                               \
                for (int cc = 0; cc < 16; ++cc) {                             \
                    int n = cc * 64 + lane;                                   \
                    const float* crow = cr0 + (size_t)n * 64;                 \
                    float dot = 0.f;                                          \
                    for (int p = 0; p < 4; ++p) {                             \
                        for (int i = 0; i < 8; ++i)                           \
                            dot = fmaf(__shfl(R0[i], mrow + 16*p), crow[p*8+i], dot); \
                        for (int i = 0; i < 8; ++i)                           \
                            dot = fmaf(__shfl(R1[i], mrow + 16*p), crow[32+p*8+i], dot); \
                    }                                                         \
                    float sc = c2s[n] - 2.f * dot;                            \
                    if (sc < bd) { bd = sc; bk = n; }                         \
                }                                                             \
                for (int off = 1; off < 64; off <<= 1) {                      \
                    float ob = __shfl_xor(bd, off); int ok = __shfl_xor(bk, off); \
                    bool tk = (ob < bd) || (ob == bd && ok < bk);             \
                    bk = tk ? ok : bk; bd = fminf(bd, ob);                    \
                }                                                             \
                if (q == lq) k1X[j] = bk;                                     \
            }                                                                 \
        }
        RESCUE(b1a, b2a, k1a, ra0, ra1)
        RESCUE(b1b, b2b, k1b, rb0, rb1)
#undef RESCUE

        // ---- transpose winners to per-lane rows (row = m), convergent ----
        int mm = m & 3, src = (m >> 2) * 16;
        int wa0 = __shfl(k1a[0], src), wa1 = __shfl(k1a[1], src);
        int wa2 = __shfl(k1a[2], src), wa3 = __shfl(k1a[3], src);
        int bka = (mm == 0) ? wa0 : (mm == 1) ? wa1 : (mm == 2) ? wa2 : wa3;
        int wb0 = __shfl(k1b[0], src), wb1 = __shfl(k1b[1], src);
        int wb2 = __shfl(k1b[2], src), wb3 = __shfl(k1b[3], src);
        int bkb = (mm == 0) ? wb0 : (mm == 1) ? wb1 : (mm == 2) ? wb2 : wb3;

        // ---- fp32 residual update (both waves, identical) ----
        const float* qa = cbf + (size_t)s * 65536 + (size_t)bka * 64;
        const float* qb = cbf + (size_t)s * 65536 + (size_t)bkb * 64;
#pragma unroll
        for (int i = 0; i < 8; ++i) {
            ra0[i] -= qa[q*8+i];  ra1[i] -= qa[32+q*8+i];
            rb0[i] -= qb[q*8+i];  rb1[i] -= qb[32+q*8+i];
        }

        // ---- loss: wave 0 stores (identical residuals in both waves) ----
        if (w == 0) {
            float ls = 0.f;
#pragma unroll
            for (int i = 0; i < 8; ++i) {
                ls = fmaf(ra0[i], ra0[i], ls); ls = fmaf(ra1[i], ra1[i], ls);
                ls = fmaf(rb0[i], rb0[i], ls); ls = fmaf(rb1[i], rb1[i], ls);
            }
#pragma unroll
            for (int off = 1; off < 64; off <<= 1) ls += __shfl_xor(ls, off);
            if (lane == 0) lossp[s * NW + wid] = ls;

            // ---- histogram: once per vector ----
            if (q == 0) {
                atomicAdd(&cnt[s * K + bka], 1u);   // vector vbase+m
                atomicAdd(&cnt[s * K + bkb], 1u);   // vector vbase+16+m
            }
        }
    }
#undef LOADTILE

    // ---- epilogue: zq = z - r_final, stores split by set across waves ----
    if (w == 0) {
#pragma unroll
        for (int i = 0; i < 8; ++i) {
            size_t a0 = zrow + ((size_t)(q*8+i)    << 12) + ta;
            size_t a1 = zrow + ((size_t)(32+q*8+i) << 12) + ta;
            zq[a0] = z[a0] - ra0[i];
            zq[a1] = z[a1] - ra1[i];
        }
    } else {
#pragma unroll
        for (int i = 0; i < 8; ++i) {
            size_t a2 = zrow + ((size_t)(q*8+i)    << 12) + tb;
            size_t a3 = zrow + ((size_t)(32+q*8+i) << 12) + tb;
            zq[a2] = z[a2] - rb0[i];
            zq[a3] = z[a3] - rb1[i];
        }
    }
}

// ---------------------------------------------------------------------------
// Finalize: losses (mean of summed wave partials) + perplexities
// ---------------------------------------------------------------------------
__global__ void rvq_finalize(const float* __restrict__ lossp,
                             const unsigned* __restrict__ cnt,
                             float* __restrict__ out_loss,
                             float* __restrict__ out_perp) {
    const int s   = blockIdx.x;
    const int tid = threadIdx.x;
    float ent = 0.f, lsum = 0.f;
    for (int i = tid; i < K; i += 256) {
        float p = (float)cnt[s * K + i] * (1.0f / 65536.0f);
        ent += p * logf(p + EPSQ);
    }
    for (int i = tid; i < NW; i += 256) lsum += lossp[s * NW + i];
    __shared__ float redE[4], redL[4];
#pragma unroll
    for (int off = 32; off > 0; off >>= 1) {
        ent  += __shfl_down(ent, off);
        lsum += __shfl_down(lsum, off);
    }
    if ((tid & 63) == 0) { redE[tid >> 6] = ent; redL[tid >> 6] = lsum; }
    __syncthreads();
    if (tid == 0) {
        float te = redE[0] + redE[1] + redE[2] + redE[3];
        float tl = redL[0] + redL[1] + redL[2] + redL[3];
        out_perp[s] = expf(-te);
        out_loss[s] = tl * (1.0f / NELEM);
    }
}

// ---------------------------------------------------------------------------
extern "C" void kernel_launch(void* const* d_in, const int* in_sizes, int n_in,
                              void* d_out, int out_size, void* d_ws, size_t ws_size,
                              hipStream_t stream) {
    const float* z  = (const float*)d_in[0];
    const float* cb = (const float*)d_in[1];

    float* zq       = (float*)d_out;
    float* out_loss = zq + 4194304;
    float* out_perp = out_loss + 8;

    // ws: cbi 2 MB | c2 32 KB | cnt 32 KB | lossp 64 KB
    char* ws = (char*)d_ws;
    unsigned short* cbi = (unsigned short*)(ws);
    float*    c2    = (float*)(ws + 2097152);
    unsigned* cnt   = (unsigned*)(ws + 2129920);
    float*    lossp = (float*)(ws + 2162688);

    hipLaunchKernelGGL(rvq_prep,     dim3(128),  dim3(256), 0, stream, cb, cbi, c2, cnt);
    hipLaunchKernelGGL(rvq_main,     dim3(NW),   dim3(128), 0, stream, z, cb, cbi, c2, zq, lossp, cnt);
    hipLaunchKernelGGL(rvq_finalize, dim3(S),    dim3(256), 0, stream, lossp, cnt, out_loss, out_perp);
}